// Round 3
// baseline (210.610 us; speedup 1.0000x reference)
//
#include <hip/hip_runtime.h>
#include <stdint.h>

// InstanceHead on MI355X — f32/int32 inputs, f32 OUTPUT buffer.
// N=100000, M=256, B=8, L=128, D=64.
// R9b: two-kernel split to break the register coupling that capped occupancy
// at 4 waves/SIMD (R7: 60 VGPR + 64 AGPR dv; R8: 72 VGPR — both land in the
// 65..128 occupancy bin; measured Occ 32%/24.6%, wave alive ~27us vs ~3us of
// issue -> latency-bound).
//   K1: GEMM1 + normalize -> bf16 clu tile [16][64], STASHED in the first
//       2KB of each tile's 16KB region of `out` (no workspace-size risk;
//       K2 reads its own stash before overwriting it -> same-wave ordering).
//   K2: distances + softmax + GEMM2.  e computed ONCE, packed f16x2 into 32
//       regs (drops R8's pass-3 sqrt/exp recompute).  inv_nrm folded into K1's
//       bf16 -> epilogue scale is 1/rsum.  All 64 stores share ONE base with
//       13-bit imm offsets (r*1024 + mt*64 <= 4032B).
// Batch validity stays geometric: x += 4096*batch (in-batch diffs cancel
// exactly; cross-batch d>=3073 -> exp underflows to exact 0; empty-row gate
// d2min < 4e6).
// (R9 compile fix: cvt_pkrtz returns __fp16 ext_vector(2), not _Float16x2.)

#define NN 100000
#define MM 256
#define LL 128
#define DD 64
#define NTILES (NN / 16)  // 6250, exact

typedef float f32x4 __attribute__((ext_vector_type(4)));
typedef __bf16 bf16x8 __attribute__((ext_vector_type(8)));
typedef __fp16 fp16x2 __attribute__((ext_vector_type(2)));

union U16x8 { uint4 u; bf16x8 v; unsigned short s[8]; };
union UH2 { unsigned int u; fp16x2 h; };

static __device__ __forceinline__ unsigned short f2bf(float f) {
  union { float f; unsigned int i; } t; t.f = f;
  unsigned int x = t.i;
  x += 0x7fffu + ((x >> 16) & 1u);  // round-to-nearest-even
  return (unsigned short)(x >> 16);
}

// ---------------- prep: cen (bf16), W^T (bf16), centroid meta ----------------
__global__ __launch_bounds__(256) void prep_kernel(
    const int* __restrict__ cen_coords,
    const float* __restrict__ cen_feats,
    const float* __restrict__ conf,
    const float* __restrict__ W,
    const float* __restrict__ bvec,
    unsigned short* __restrict__ cen_ws,   // [256][64] bf16
    unsigned short* __restrict__ wt_ws,    // [64][128] bf16 (W transposed)
    float4* __restrict__ cmeta_ws)         // [256] {x+4096*batch, y, z, 0}
{
  int tid = threadIdx.x;
  if (blockIdx.x < 16) {
    int m = blockIdx.x * 16 + (tid >> 4);
    int c = tid & 15;
    float a0 = 0.f, a1 = 0.f, a2 = 0.f, a3 = 0.f;
    for (int l = 0; l < LL; l++) {
      float f = cen_feats[m * LL + l];
      const float* wr = W + l * DD + c;
      a0 += f * wr[0];  a1 += f * wr[16];
      a2 += f * wr[32]; a3 += f * wr[48];
    }
    float cf = conf[m];
    cen_ws[m * DD + c +  0] = f2bf(cf * (a0 + bvec[c +  0]));
    cen_ws[m * DD + c + 16] = f2bf(cf * (a1 + bvec[c + 16]));
    cen_ws[m * DD + c + 32] = f2bf(cf * (a2 + bvec[c + 32]));
    cen_ws[m * DD + c + 48] = f2bf(cf * (a3 + bvec[c + 48]));
  } else {
    for (int i = tid; i < LL * DD; i += 256) {
      int l = i >> 6, d = i & 63;
      wt_ws[d * LL + l] = f2bf(W[l * DD + d]);
    }
    {
      int4 cc = ((const int4*)cen_coords)[tid];  // {batch, x, y, z}
      float4 f;
      f.x = (float)cc.y + 4096.0f * (float)cc.x;  // batch folded into x
      f.y = (float)cc.z;
      f.z = (float)cc.w;
      f.w = 0.0f;
      cmeta_ws[tid] = f;
    }
  }
}

// ---------------- K1: GEMM1 + row-normalize -> bf16 stash in out ----------------
__global__ __launch_bounds__(256, 8) void k1_gemm1(
    const float* __restrict__ feats,
    const float* __restrict__ bvec,
    const unsigned short* __restrict__ wt_ws,
    float* __restrict__ out)
{
  __shared__ __align__(16) unsigned short clu_s[4][16 * 72];  // wave-private

  int tid = threadIdx.x;
  int wave = tid >> 6, lane = tid & 63;
  int q = lane >> 4, c = lane & 15;
  int tile = blockIdx.x * 4 + wave;
  if (tile >= NTILES) return;

  f32x4 acc[4] = {{0,0,0,0},{0,0,0,0},{0,0,0,0},{0,0,0,0}};
  {
    const float4* fb = (const float4*)(feats + (size_t)(tile * 16 + c) * LL);
    const uint4* wb = (const uint4*)wt_ws;
#pragma unroll
    for (int ks = 0; ks < 4; ks++) {
      float4 f0 = fb[ks * 8 + q * 2];
      float4 f1 = fb[ks * 8 + q * 2 + 1];
      U16x8 a;
      a.v[0] = (__bf16)f0.x; a.v[1] = (__bf16)f0.y; a.v[2] = (__bf16)f0.z; a.v[3] = (__bf16)f0.w;
      a.v[4] = (__bf16)f1.x; a.v[5] = (__bf16)f1.y; a.v[6] = (__bf16)f1.z; a.v[7] = (__bf16)f1.w;
#pragma unroll
      for (int nt = 0; nt < 4; nt++) {
        U16x8 b; b.u = wb[(nt * 16 + c) * 16 + ks * 4 + q];
        acc[nt] = __builtin_amdgcn_mfma_f32_16x16x32_bf16(a.v, b.v, acc[nt], 0, 0, 0);
      }
    }
  }
#pragma unroll
  for (int nt = 0; nt < 4; nt++) {
    float bv = bvec[nt * 16 + c];
    acc[nt][0] += bv; acc[nt][1] += bv; acc[nt][2] += bv; acc[nt][3] += bv;
  }
  // row L2 norms (row r = q*4+r lives across the 16 lanes of quad q)
  float inv_nrm[4];
#pragma unroll
  for (int r = 0; r < 4; r++) {
    float s = acc[0][r]*acc[0][r] + acc[1][r]*acc[1][r] + acc[2][r]*acc[2][r] + acc[3][r]*acc[3][r];
    s += __shfl_xor(s, 1); s += __shfl_xor(s, 2); s += __shfl_xor(s, 4); s += __shfl_xor(s, 8);
    inv_nrm[r] = 1.0f / fmaxf(sqrtf(s), 1e-12f);
  }
  // normalized clu -> LDS (bf16), 72-short rows (bank-stagger)
#pragma unroll
  for (int nt = 0; nt < 4; nt++)
#pragma unroll
    for (int r = 0; r < 4; r++) {
      union { __bf16 h; unsigned short s; } u;
      u.h = (__bf16)(acc[nt][r] * inv_nrm[r]);
      clu_s[wave][(q * 4 + r) * 72 + nt * 16 + c] = u.s;
    }

  // wave-private LDS transpose: DS pipe is in-order per wave, no barrier
  __builtin_amdgcn_sched_barrier(0);

  // compact readback: lane covers 32B = row lane/4, cols (lane%4)*16..+15
  const uint4* cb = (const uint4*)(clu_s[wave]);
  uint4 s0 = cb[(lane >> 2) * 9 + (lane & 3) * 2];
  uint4 s1 = cb[(lane >> 2) * 9 + (lane & 3) * 2 + 1];
  uint4* stash = (uint4*)((char*)out + (size_t)tile * 16384);
  stash[lane * 2]     = s0;
  stash[lane * 2 + 1] = s1;
}

// ---------------- K2: distances + softmax + GEMM2 (no LDS) ----------------
__global__ __launch_bounds__(256, 6) void k2_attn(
    const int4* __restrict__ clu_coords4,
    const unsigned short* __restrict__ cen_ws,
    const float4* __restrict__ cmeta,
    float* __restrict__ out)
{
  int tid = threadIdx.x;
  int wave = tid >> 6, lane = tid & 63;
  int q = lane >> 4, c = lane & 15;
  int tile = blockIdx.x * 4 + wave;
  if (tile >= NTILES) return;

  // A-frags from this tile's stash (read BEFORE any store to this region;
  // the first MFMA's waitcnt orders load-completion ahead of all stores)
  const uint4* stash = (const uint4*)((const char*)out + (size_t)tile * 16384);
  U16x8 a0, a1;
  a0.u = stash[c * 8 + q];       // row c, k = q*8..q*8+7
  a1.u = stash[c * 8 + 4 + q];   // row c, k = 32+q*8..

  // row meta for this lane's 4 C-rows (batch folded into x, exact)
  float rx[4], ry[4], rz[4];
#pragma unroll
  for (int r = 0; r < 4; r++) {
    int4 rm = clu_coords4[tile * 16 + q * 4 + r];
    rx[r] = (float)rm.y + 4096.0f * (float)rm.x;
    ry[r] = (float)rm.z;
    rz[r] = (float)rm.w;
  }

  // ---- pass 1: d^2 min (rolled — no reg array indexed by mt)
  float d2m[4] = {1e30f, 1e30f, 1e30f, 1e30f};
#pragma unroll 4
  for (int mt = 0; mt < 16; mt++) {
    float4 cm = cmeta[mt * 16 + c];
#pragma unroll
    for (int r = 0; r < 4; r++) {
      float dx = rx[r] - cm.x, dy = ry[r] - cm.y, dz = rz[r] - cm.z;
      d2m[r] = fminf(d2m[r], dx * dx + dy * dy + dz * dz);
    }
  }
  float dmv[4];
#pragma unroll
  for (int r = 0; r < 4; r++) {
    d2m[r] = fminf(d2m[r], __shfl_xor(d2m[r], 1));
    d2m[r] = fminf(d2m[r], __shfl_xor(d2m[r], 2));
    d2m[r] = fminf(d2m[r], __shfl_xor(d2m[r], 4));
    d2m[r] = fminf(d2m[r], __shfl_xor(d2m[r], 8));
    dmv[r] = fmaxf(sqrtf(d2m[r]), 0.1f);  // softmax reference (row min dist)
  }

  // ---- pass 2: e = exp(dmin - d) ONCE; pack f16x2 (32 regs); row sums
  //      (fully unrolled: ep[] must be statically indexed — rule #20)
  uint2 ep[16];
  float rsum[4] = {0.f, 0.f, 0.f, 0.f};
#pragma unroll
  for (int mt = 0; mt < 16; mt++) {
    float4 cm = cmeta[mt * 16 + c];
    float e[4];
#pragma unroll
    for (int r = 0; r < 4; r++) {
      float dx = rx[r] - cm.x, dy = ry[r] - cm.y, dz = rz[r] - cm.z;
      float d = fmaxf(sqrtf(dx * dx + dy * dy + dz * dz), 0.1f);
      e[r] = __expf(dmv[r] - d);  // <= 1; cross-batch -> exact 0
      rsum[r] += e[r];
    }
    UH2 p0, p1;
    p0.h = __builtin_amdgcn_cvt_pkrtz(e[0], e[1]);
    p1.h = __builtin_amdgcn_cvt_pkrtz(e[2], e[3]);
    ep[mt].x = p0.u;
    ep[mt].y = p1.u;
  }
  float scale[4];
#pragma unroll
  for (int r = 0; r < 4; r++) {
    rsum[r] += __shfl_xor(rsum[r], 1);
    rsum[r] += __shfl_xor(rsum[r], 2);
    rsum[r] += __shfl_xor(rsum[r], 4);
    rsum[r] += __shfl_xor(rsum[r], 8);
    // d2m >= 4e6 <=> no same-batch centroid for this row -> exact-zero row
    // (inv_nrm already folded into the bf16 A-frags by K1)
    scale[r] = (d2m[r] < 4.0e6f) ? 1.0f / rsum[r] : 0.f;
  }

  // ---- pass 3: GEMM2 + unpack e + store.  ONE base, imm offsets
  //      (r*1024 + mt*64 bytes <= 4032 < 4096)
  const uint4* cenb = (const uint4*)cen_ws;
  float* ob = out + (size_t)(tile * 16 + q * 4) * MM + c;
#pragma unroll
  for (int mt = 0; mt < 16; mt++) {
    U16x8 b0, b1;
    b0.u = cenb[(mt * 16 + c) * 8 + q];
    b1.u = cenb[(mt * 16 + c) * 8 + 4 + q];
    f32x4 dacc = {0, 0, 0, 0};
    dacc = __builtin_amdgcn_mfma_f32_16x16x32_bf16(a0.v, b0.v, dacc, 0, 0, 0);
    dacc = __builtin_amdgcn_mfma_f32_16x16x32_bf16(a1.v, b1.v, dacc, 0, 0, 0);
    UH2 p0, p1; p0.u = ep[mt].x; p1.u = ep[mt].y;
    ob[0 * MM + mt * 16] = dacc[0] * ((float)p0.h[0] * scale[0]);
    ob[1 * MM + mt * 16] = dacc[1] * ((float)p0.h[1] * scale[1]);
    ob[2 * MM + mt * 16] = dacc[2] * ((float)p1.h[0] * scale[2]);
    ob[3 * MM + mt * 16] = dacc[3] * ((float)p1.h[1] * scale[3]);
  }
}

extern "C" void kernel_launch(void* const* d_in, const int* in_sizes, int n_in,
                              void* d_out, int out_size, void* d_ws, size_t ws_size,
                              hipStream_t stream) {
  const int* clu_coords = (const int*)d_in[0];
  const int* cen_coords = (const int*)d_in[1];
  const float* clu_feats = (const float*)d_in[2];
  const float* cen_feats = (const float*)d_in[3];
  const float* conf      = (const float*)d_in[4];
  const float* W         = (const float*)d_in[5];
  const float* bvec      = (const float*)d_in[6];
  float* out = (float*)d_out;

  char* ws = (char*)d_ws;
  unsigned short* cen_ws = (unsigned short*)ws;              // 32768 B
  unsigned short* wt_ws  = (unsigned short*)(ws + 32768);    // 16384 B
  float4* cmeta_ws       = (float4*)(ws + 32768 + 16384);    // 4096 B

  prep_kernel<<<17, 256, 0, stream>>>(cen_coords, cen_feats, conf, W, bvec,
                                      cen_ws, wt_ws, cmeta_ws);
  int nblk = (NTILES + 3) / 4;
  k1_gemm1<<<nblk, 256, 0, stream>>>(clu_feats, bvec, wt_ws, out);
  k2_attn<<<nblk, 256, 0, stream>>>((const int4*)clu_coords, cen_ws, cmeta_ws, out);
}

// Round 5
// 208.961 us; speedup vs baseline: 1.0079x; 1.0079x over previous
//
#include <hip/hip_runtime.h>
#include <stdint.h>

// InstanceHead on MI355X — f32/int32 inputs, f32 OUTPUT buffer.
// N=100000, M=256, B=8, L=128, D=64.
// R10b: fused (R9 split lost: stash round-trip + drain).  R10's fix:
// inv_nrm was applied twice (LDS write AND epilogue).  Now: normalization
// folded into the LDS bf16 write ONLY; epilogue scale = 1/rsum (gated).
//   - attention weights packed f16x2 -> 32 regs (R7's dv was 64 f32 AGPRs)
//   - batch validity folded into geometry (x += 4096*batch; exact in-batch,
//     cross-batch exp underflows to exact 0; empty-row gate d2min < 4e6)
//   - ILP: feats + coord loads issued FIRST, distance passes (L1-hot cmeta)
//     run while they're in flight, then GEMM1 -> LDS transpose -> GEMM2.
//   - __launch_bounds__(256,4): pin the 128-VGPR bin (4 waves/SIMD).
// Wave-autonomous, zero block barriers (LDS slice is wave-private).

#define NN 100000
#define MM 256
#define LL 128
#define DD 64
#define NTILES (NN / 16)  // 6250, exact

typedef float f32x4 __attribute__((ext_vector_type(4)));
typedef __bf16 bf16x8 __attribute__((ext_vector_type(8)));
typedef __fp16 fp16x2 __attribute__((ext_vector_type(2)));

union U16x8 { uint4 u; bf16x8 v; unsigned short s[8]; };
union UH2 { unsigned int u; fp16x2 h; };

static __device__ __forceinline__ unsigned short f2bf(float f) {
  union { float f; unsigned int i; } t; t.f = f;
  unsigned int x = t.i;
  x += 0x7fffu + ((x >> 16) & 1u);  // round-to-nearest-even
  return (unsigned short)(x >> 16);
}

// ---------------- prep: cen (bf16), W^T (bf16), centroid meta ----------------
__global__ __launch_bounds__(256) void prep_kernel(
    const int* __restrict__ cen_coords,
    const float* __restrict__ cen_feats,
    const float* __restrict__ conf,
    const float* __restrict__ W,
    const float* __restrict__ bvec,
    unsigned short* __restrict__ cen_ws,   // [256][64] bf16
    unsigned short* __restrict__ wt_ws,    // [64][128] bf16 (W transposed)
    float4* __restrict__ cmeta_ws)         // [256] {x+4096*batch, y, z, 0}
{
  int tid = threadIdx.x;
  if (blockIdx.x < 16) {
    int m = blockIdx.x * 16 + (tid >> 4);
    int c = tid & 15;
    float a0 = 0.f, a1 = 0.f, a2 = 0.f, a3 = 0.f;
    for (int l = 0; l < LL; l++) {
      float f = cen_feats[m * LL + l];
      const float* wr = W + l * DD + c;
      a0 += f * wr[0];  a1 += f * wr[16];
      a2 += f * wr[32]; a3 += f * wr[48];
    }
    float cf = conf[m];
    cen_ws[m * DD + c +  0] = f2bf(cf * (a0 + bvec[c +  0]));
    cen_ws[m * DD + c + 16] = f2bf(cf * (a1 + bvec[c + 16]));
    cen_ws[m * DD + c + 32] = f2bf(cf * (a2 + bvec[c + 32]));
    cen_ws[m * DD + c + 48] = f2bf(cf * (a3 + bvec[c + 48]));
  } else {
    for (int i = tid; i < LL * DD; i += 256) {
      int l = i >> 6, d = i & 63;
      wt_ws[d * LL + l] = f2bf(W[l * DD + d]);
    }
    {
      int4 cc = ((const int4*)cen_coords)[tid];  // {batch, x, y, z}
      float4 f;
      f.x = (float)cc.y + 4096.0f * (float)cc.x;  // batch folded into x
      f.y = (float)cc.z;
      f.z = (float)cc.w;
      f.w = 0.0f;
      cmeta_ws[tid] = f;
    }
  }
}

// ---------------- main: fused, 1 wave per 16-row tile, no barrier ----------------
__global__ __launch_bounds__(256, 4) void main_kernel(
    const int4* __restrict__ clu_coords4,
    const float* __restrict__ feats,
    const float* __restrict__ bvec,
    const unsigned short* __restrict__ cen_ws,
    const unsigned short* __restrict__ wt_ws,
    const float4* __restrict__ cmeta,
    float* __restrict__ out)
{
  __shared__ __align__(16) unsigned short clu_s[4][16 * 72];  // wave-private

  int tid = threadIdx.x;
  int wave = tid >> 6, lane = tid & 63;
  int q = lane >> 4, c = lane & 15;
  int tile = blockIdx.x * 4 + wave;
  if (tile >= NTILES) return;

  // ---- issue the long-latency loads FIRST: feats (8x float4, 32 regs in
  //      flight) + this lane's 4 coord rows.  Distance passes below (L1-hot
  //      cmeta) execute while these are outstanding.
  const float4* fb = (const float4*)(feats + (size_t)(tile * 16 + c) * LL);
  float4 ff[8];
#pragma unroll
  for (int ks = 0; ks < 4; ks++) {
    ff[2 * ks]     = fb[ks * 8 + q * 2];
    ff[2 * ks + 1] = fb[ks * 8 + q * 2 + 1];
  }
  float rx[4], ry[4], rz[4];
#pragma unroll
  for (int r = 0; r < 4; r++) {
    int4 rm = clu_coords4[tile * 16 + q * 4 + r];
    rx[r] = (float)rm.y + 4096.0f * (float)rm.x;  // batch folded into x
    ry[r] = (float)rm.z;
    rz[r] = (float)rm.w;
  }

  // ---- pass 1: d^2 min (rolled — nothing stored)
  float d2m[4] = {1e30f, 1e30f, 1e30f, 1e30f};
#pragma unroll 4
  for (int mt = 0; mt < 16; mt++) {
    float4 cm = cmeta[mt * 16 + c];
#pragma unroll
    for (int r = 0; r < 4; r++) {
      float dx = rx[r] - cm.x, dy = ry[r] - cm.y, dz = rz[r] - cm.z;
      d2m[r] = fminf(d2m[r], dx * dx + dy * dy + dz * dz);
    }
  }
  float dmv[4];
#pragma unroll
  for (int r = 0; r < 4; r++) {
    d2m[r] = fminf(d2m[r], __shfl_xor(d2m[r], 1));
    d2m[r] = fminf(d2m[r], __shfl_xor(d2m[r], 2));
    d2m[r] = fminf(d2m[r], __shfl_xor(d2m[r], 4));
    d2m[r] = fminf(d2m[r], __shfl_xor(d2m[r], 8));
    dmv[r] = fmaxf(sqrtf(d2m[r]), 0.1f);  // softmax reference (row min dist)
  }

  // ---- pass 2: e = exp(dmin - d) ONCE; pack f16x2 (32 regs); row sums
  uint2 ep[16];
  float rsum[4] = {0.f, 0.f, 0.f, 0.f};
#pragma unroll
  for (int mt = 0; mt < 16; mt++) {
    float4 cm = cmeta[mt * 16 + c];
    float e[4];
#pragma unroll
    for (int r = 0; r < 4; r++) {
      float dx = rx[r] - cm.x, dy = ry[r] - cm.y, dz = rz[r] - cm.z;
      float d = fmaxf(sqrtf(dx * dx + dy * dy + dz * dz), 0.1f);
      e[r] = __expf(dmv[r] - d);  // <= 1; cross-batch -> exact 0
      rsum[r] += e[r];
    }
    UH2 p0, p1;
    p0.h = __builtin_amdgcn_cvt_pkrtz(e[0], e[1]);
    p1.h = __builtin_amdgcn_cvt_pkrtz(e[2], e[3]);
    ep[mt].x = p0.u;
    ep[mt].y = p1.u;
  }
  float sc[4];
#pragma unroll
  for (int r = 0; r < 4; r++) {
    rsum[r] += __shfl_xor(rsum[r], 1);
    rsum[r] += __shfl_xor(rsum[r], 2);
    rsum[r] += __shfl_xor(rsum[r], 4);
    rsum[r] += __shfl_xor(rsum[r], 8);
    // d2m >= 4e6 <=> no same-batch centroid -> exact-zero row.
    // inv_nrm is folded into the LDS bf16 A-frags below — NOT here (R10 bug).
    sc[r] = (d2m[r] < 4.0e6f) ? 1.0f / rsum[r] : 0.f;
  }

  // ---- GEMM1: clu = feats @ W (+b); feats arrived during the passes above
  f32x4 acc[4] = {{0,0,0,0},{0,0,0,0},{0,0,0,0},{0,0,0,0}};
  {
    const uint4* wb = (const uint4*)wt_ws;
#pragma unroll
    for (int ks = 0; ks < 4; ks++) {
      float4 f0 = ff[2 * ks], f1 = ff[2 * ks + 1];
      U16x8 a;
      a.v[0] = (__bf16)f0.x; a.v[1] = (__bf16)f0.y; a.v[2] = (__bf16)f0.z; a.v[3] = (__bf16)f0.w;
      a.v[4] = (__bf16)f1.x; a.v[5] = (__bf16)f1.y; a.v[6] = (__bf16)f1.z; a.v[7] = (__bf16)f1.w;
#pragma unroll
      for (int nt = 0; nt < 4; nt++) {
        U16x8 b; b.u = wb[(nt * 16 + c) * 16 + ks * 4 + q];
        acc[nt] = __builtin_amdgcn_mfma_f32_16x16x32_bf16(a.v, b.v, acc[nt], 0, 0, 0);
      }
    }
  }
#pragma unroll
  for (int nt = 0; nt < 4; nt++) {
    float bv = bvec[nt * 16 + c];
    acc[nt][0] += bv; acc[nt][1] += bv; acc[nt][2] += bv; acc[nt][3] += bv;
  }
  // row L2 norms (row r = q*4+r lives across the 16 lanes of quad q)
  float inv_nrm[4];
#pragma unroll
  for (int r = 0; r < 4; r++) {
    float s = acc[0][r]*acc[0][r] + acc[1][r]*acc[1][r] + acc[2][r]*acc[2][r] + acc[3][r]*acc[3][r];
    s += __shfl_xor(s, 1); s += __shfl_xor(s, 2); s += __shfl_xor(s, 4); s += __shfl_xor(s, 8);
    inv_nrm[r] = 1.0f / fmaxf(sqrtf(s), 1e-12f);
  }
  // normalized clu -> LDS (bf16), 72-short rows (bank-stagger).
  // inv_nrm applied HERE only.
#pragma unroll
  for (int nt = 0; nt < 4; nt++)
#pragma unroll
    for (int r = 0; r < 4; r++) {
      union { __bf16 h; unsigned short s; } u;
      u.h = (__bf16)(acc[nt][r] * inv_nrm[r]);
      clu_s[wave][(q * 4 + r) * 72 + nt * 16 + c] = u.s;
    }

  // wave-private LDS transpose: DS pipe is in-order per wave, no barrier
  __builtin_amdgcn_sched_barrier(0);

  // ---- GEMM2 A-frags from LDS
  const uint4* cb = (const uint4*)(clu_s[wave]);
  U16x8 a0, a1;
  a0.u = cb[c * 9 + q];       // row c, k = q*8..q*8+7
  a1.u = cb[c * 9 + 4 + q];   // row c, k = 32+q*8..

  // ---- GEMM2 + unpack e + store.  ONE base, imm offsets
  //      (r*1024 + mt*64 bytes <= 4032 < 4096)
  const uint4* cenb = (const uint4*)cen_ws;
  float* ob = out + (size_t)(tile * 16 + q * 4) * MM + c;
#pragma unroll
  for (int mt = 0; mt < 16; mt++) {
    U16x8 b0, b1;
    b0.u = cenb[(mt * 16 + c) * 8 + q];
    b1.u = cenb[(mt * 16 + c) * 8 + 4 + q];
    f32x4 dacc = {0, 0, 0, 0};
    dacc = __builtin_amdgcn_mfma_f32_16x16x32_bf16(a0.v, b0.v, dacc, 0, 0, 0);
    dacc = __builtin_amdgcn_mfma_f32_16x16x32_bf16(a1.v, b1.v, dacc, 0, 0, 0);
    UH2 p0, p1; p0.u = ep[mt].x; p1.u = ep[mt].y;
    ob[0 * MM + mt * 16] = dacc[0] * ((float)p0.h[0] * sc[0]);
    ob[1 * MM + mt * 16] = dacc[1] * ((float)p0.h[1] * sc[1]);
    ob[2 * MM + mt * 16] = dacc[2] * ((float)p1.h[0] * sc[2]);
    ob[3 * MM + mt * 16] = dacc[3] * ((float)p1.h[1] * sc[3]);
  }
}

extern "C" void kernel_launch(void* const* d_in, const int* in_sizes, int n_in,
                              void* d_out, int out_size, void* d_ws, size_t ws_size,
                              hipStream_t stream) {
  const int* clu_coords = (const int*)d_in[0];
  const int* cen_coords = (const int*)d_in[1];
  const float* clu_feats = (const float*)d_in[2];
  const float* cen_feats = (const float*)d_in[3];
  const float* conf      = (const float*)d_in[4];
  const float* W         = (const float*)d_in[5];
  const float* bvec      = (const float*)d_in[6];
  float* out = (float*)d_out;

  char* ws = (char*)d_ws;
  unsigned short* cen_ws = (unsigned short*)ws;              // 32768 B
  unsigned short* wt_ws  = (unsigned short*)(ws + 32768);    // 16384 B
  float4* cmeta_ws       = (float4*)(ws + 32768 + 16384);    // 4096 B

  prep_kernel<<<17, 256, 0, stream>>>(cen_coords, cen_feats, conf, W, bvec,
                                      cen_ws, wt_ws, cmeta_ws);
  main_kernel<<<(NTILES + 3) / 4, 256, 0, stream>>>(
      (const int4*)clu_coords, clu_feats, bvec, cen_ws, wt_ws, cmeta_ws, out);
}

// Round 6
// 202.624 us; speedup vs baseline: 1.0394x; 1.0313x over previous
//
#include <hip/hip_runtime.h>
#include <stdint.h>

// InstanceHead on MI355X — f32/int32 inputs, f32 OUTPUT buffer.
// N=100000, M=256, B=8, L=128, D=64.
// R11: software-pipelined 2 tiles/wave (R7 phase order, which measured
// fastest).  Evidence: R7/R8/R10b all sit 77-85us with VALUBusy ~35%,
// Occ ~31%, regardless of register shuffling — pure exposed latency, and a
// block's 4 waves hit their 8KB feats load in lockstep.  R11:
//   - each wave owns tiles (2j, 2j+1); after GEMM1(A) consumes ff, ff is
//     immediately reloaded with tile B's feats -> the load overlaps tile A's
//     norm/distance/epilogue (~2000+ cyc, no ff dependence).  Only the first
//     load per wave is exposed.  Waves also desynchronize after iter 0.
//   - cmeta staged in LDS per block (4KB, one barrier before divergence):
//     64 thrash-prone L1/L2 loads/wave -> deterministic ds_reads (2-way
//     conflicts only = free).  cen_ws stays global.
//   - ep packed f16x2 (32 regs), geometric batch fold (x += 4096*batch),
//     imm-offset stores.  Plain __launch_bounds__(256).
// Wave-autonomous after the one staging barrier; LDS clu slice is
// wave-private (in-order DS pipe; tile B writes follow tile A reads in
// program order -> no barrier).

#define NN 100000
#define MM 256
#define LL 128
#define DD 64
#define NTILES (NN / 16)    // 6250, exact
#define NJOBS (NTILES / 2)  // 3125, exact

typedef float f32x4 __attribute__((ext_vector_type(4)));
typedef __bf16 bf16x8 __attribute__((ext_vector_type(8)));
typedef __fp16 fp16x2 __attribute__((ext_vector_type(2)));

union U16x8 { uint4 u; bf16x8 v; unsigned short s[8]; };
union UH2 { unsigned int u; fp16x2 h; };

static __device__ __forceinline__ unsigned short f2bf(float f) {
  union { float f; unsigned int i; } t; t.f = f;
  unsigned int x = t.i;
  x += 0x7fffu + ((x >> 16) & 1u);  // round-to-nearest-even
  return (unsigned short)(x >> 16);
}

// ---------------- prep: cen (bf16), W^T (bf16), centroid meta ----------------
__global__ __launch_bounds__(256) void prep_kernel(
    const int* __restrict__ cen_coords,
    const float* __restrict__ cen_feats,
    const float* __restrict__ conf,
    const float* __restrict__ W,
    const float* __restrict__ bvec,
    unsigned short* __restrict__ cen_ws,   // [256][64] bf16
    unsigned short* __restrict__ wt_ws,    // [64][128] bf16 (W transposed)
    float4* __restrict__ cmeta_ws)         // [256] {x+4096*batch, y, z, 0}
{
  int tid = threadIdx.x;
  if (blockIdx.x < 16) {
    int m = blockIdx.x * 16 + (tid >> 4);
    int c = tid & 15;
    float a0 = 0.f, a1 = 0.f, a2 = 0.f, a3 = 0.f;
    for (int l = 0; l < LL; l++) {
      float f = cen_feats[m * LL + l];
      const float* wr = W + l * DD + c;
      a0 += f * wr[0];  a1 += f * wr[16];
      a2 += f * wr[32]; a3 += f * wr[48];
    }
    float cf = conf[m];
    cen_ws[m * DD + c +  0] = f2bf(cf * (a0 + bvec[c +  0]));
    cen_ws[m * DD + c + 16] = f2bf(cf * (a1 + bvec[c + 16]));
    cen_ws[m * DD + c + 32] = f2bf(cf * (a2 + bvec[c + 32]));
    cen_ws[m * DD + c + 48] = f2bf(cf * (a3 + bvec[c + 48]));
  } else {
    for (int i = tid; i < LL * DD; i += 256) {
      int l = i >> 6, d = i & 63;
      wt_ws[d * LL + l] = f2bf(W[l * DD + d]);
    }
    {
      int4 cc = ((const int4*)cen_coords)[tid];  // {batch, x, y, z}
      float4 f;
      f.x = (float)cc.y + 4096.0f * (float)cc.x;  // batch folded into x
      f.y = (float)cc.z;
      f.z = (float)cc.w;
      f.w = 0.0f;
      cmeta_ws[tid] = f;
    }
  }
}

// ---------------- main: 1 wave = 2 tiles, software-pipelined ----------------
__global__ __launch_bounds__(256) void main_kernel(
    const int4* __restrict__ clu_coords4,
    const float* __restrict__ feats,
    const float* __restrict__ bvec,
    const unsigned short* __restrict__ cen_ws,
    const unsigned short* __restrict__ wt_ws,
    const float4* __restrict__ cmeta,
    float* __restrict__ out)
{
  __shared__ __align__(16) unsigned short clu_s[4][16 * 72];  // wave-private
  __shared__ __align__(16) float4 cmeta_s[MM];                // block-shared

  int tid = threadIdx.x;
  // stage cmeta once per block (before any divergent exit)
  cmeta_s[tid] = cmeta[tid];
  __syncthreads();

  int wave = tid >> 6, lane = tid & 63;
  int q = lane >> 4, c = lane & 15;
  int job = blockIdx.x * 4 + wave;
  if (job >= NJOBS) return;
  int tile0 = job * 2;

  // ---- prologue: tile A feats (the only exposed feats load per wave)
  const float4* fb = (const float4*)(feats + (size_t)(tile0 * 16 + c) * LL);
  float4 ff[8];
#pragma unroll
  for (int ks = 0; ks < 4; ks++) {
    ff[2 * ks]     = fb[ks * 8 + q * 2];
    ff[2 * ks + 1] = fb[ks * 8 + q * 2 + 1];
  }

#pragma unroll
  for (int tt = 0; tt < 2; tt++) {
    int tile = tile0 + tt;

    // current tile's coords — issued before GEMM1 so the MFMA burst covers it
    int4 rm[4];
#pragma unroll
    for (int r = 0; r < 4; r++)
      rm[r] = clu_coords4[tile * 16 + q * 4 + r];

    // ---- GEMM1: clu = feats @ W (+b), consumes ff
    f32x4 acc[4] = {{0,0,0,0},{0,0,0,0},{0,0,0,0},{0,0,0,0}};
    {
      const uint4* wb = (const uint4*)wt_ws;
#pragma unroll
      for (int ks = 0; ks < 4; ks++) {
        float4 f0 = ff[2 * ks], f1 = ff[2 * ks + 1];
        U16x8 a;
        a.v[0] = (__bf16)f0.x; a.v[1] = (__bf16)f0.y; a.v[2] = (__bf16)f0.z; a.v[3] = (__bf16)f0.w;
        a.v[4] = (__bf16)f1.x; a.v[5] = (__bf16)f1.y; a.v[6] = (__bf16)f1.z; a.v[7] = (__bf16)f1.w;
#pragma unroll
        for (int nt = 0; nt < 4; nt++) {
          U16x8 b; b.u = wb[(nt * 16 + c) * 16 + ks * 4 + q];
          acc[nt] = __builtin_amdgcn_mfma_f32_16x16x32_bf16(a.v, b.v, acc[nt], 0, 0, 0);
        }
      }
    }

    // ---- prefetch tile B's feats into the same ff regs (tt==0 only);
    //      overlaps everything below (norms, distances, epilogue of tile A)
    if (tt == 0) {
#pragma unroll
      for (int ks = 0; ks < 4; ks++) {
        ff[2 * ks]     = fb[512 + ks * 8 + q * 2];      // +16 rows * 128 f32
        ff[2 * ks + 1] = fb[512 + ks * 8 + q * 2 + 1];
      }
    }

    // ---- bias + row L2 norms
#pragma unroll
    for (int nt = 0; nt < 4; nt++) {
      float bv = bvec[nt * 16 + c];
      acc[nt][0] += bv; acc[nt][1] += bv; acc[nt][2] += bv; acc[nt][3] += bv;
    }
    float inv_nrm[4];
#pragma unroll
    for (int r = 0; r < 4; r++) {
      float s = acc[0][r]*acc[0][r] + acc[1][r]*acc[1][r] + acc[2][r]*acc[2][r] + acc[3][r]*acc[3][r];
      s += __shfl_xor(s, 1); s += __shfl_xor(s, 2); s += __shfl_xor(s, 4); s += __shfl_xor(s, 8);
      inv_nrm[r] = 1.0f / fmaxf(sqrtf(s), 1e-12f);
    }
    // normalized clu -> LDS (bf16); inv_nrm applied HERE only
#pragma unroll
    for (int nt = 0; nt < 4; nt++)
#pragma unroll
      for (int r = 0; r < 4; r++) {
        union { __bf16 h; unsigned short s; } u;
        u.h = (__bf16)(acc[nt][r] * inv_nrm[r]);
        clu_s[wave][(q * 4 + r) * 72 + nt * 16 + c] = u.s;
      }

    // wave-private LDS transpose: DS pipe is in-order per wave, no barrier.
    // (Across tt iterations: tile B writes follow tile A reads in program
    // order on the same in-order pipe — safe.)
    __builtin_amdgcn_sched_barrier(0);

    const uint4* cb = (const uint4*)(clu_s[wave]);
    U16x8 a0, a1;
    a0.u = cb[c * 9 + q];       // row c, k = q*8..q*8+7
    a1.u = cb[c * 9 + 4 + q];   // row c, k = 32+q*8..

    // ---- coords -> float (batch folded into x, exact)
    float rx[4], ry[4], rz[4];
#pragma unroll
    for (int r = 0; r < 4; r++) {
      rx[r] = (float)rm[r].y + 4096.0f * (float)rm[r].x;
      ry[r] = (float)rm[r].z;
      rz[r] = (float)rm[r].w;
    }

    // ---- pass 1: d^2 min (cmeta from LDS)
    float d2m[4] = {1e30f, 1e30f, 1e30f, 1e30f};
#pragma unroll 4
    for (int mt = 0; mt < 16; mt++) {
      float4 cm = cmeta_s[mt * 16 + c];
#pragma unroll
      for (int r = 0; r < 4; r++) {
        float dx = rx[r] - cm.x, dy = ry[r] - cm.y, dz = rz[r] - cm.z;
        d2m[r] = fminf(d2m[r], dx * dx + dy * dy + dz * dz);
      }
    }
    float dmv[4];
#pragma unroll
    for (int r = 0; r < 4; r++) {
      d2m[r] = fminf(d2m[r], __shfl_xor(d2m[r], 1));
      d2m[r] = fminf(d2m[r], __shfl_xor(d2m[r], 2));
      d2m[r] = fminf(d2m[r], __shfl_xor(d2m[r], 4));
      d2m[r] = fminf(d2m[r], __shfl_xor(d2m[r], 8));
      dmv[r] = fmaxf(sqrtf(d2m[r]), 0.1f);  // softmax reference (row min dist)
    }

    // ---- pass 2: e = exp(dmin - d) once; pack f16x2; row sums
    uint2 ep[16];
    float rsum[4] = {0.f, 0.f, 0.f, 0.f};
#pragma unroll
    for (int mt = 0; mt < 16; mt++) {
      float4 cm = cmeta_s[mt * 16 + c];
      float e[4];
#pragma unroll
      for (int r = 0; r < 4; r++) {
        float dx = rx[r] - cm.x, dy = ry[r] - cm.y, dz = rz[r] - cm.z;
        float d = fmaxf(sqrtf(dx * dx + dy * dy + dz * dz), 0.1f);
        e[r] = __expf(dmv[r] - d);  // <= 1; cross-batch -> exact 0
        rsum[r] += e[r];
      }
      UH2 p0, p1;
      p0.h = __builtin_amdgcn_cvt_pkrtz(e[0], e[1]);
      p1.h = __builtin_amdgcn_cvt_pkrtz(e[2], e[3]);
      ep[mt].x = p0.u;
      ep[mt].y = p1.u;
    }
    float sc[4];
#pragma unroll
    for (int r = 0; r < 4; r++) {
      rsum[r] += __shfl_xor(rsum[r], 1);
      rsum[r] += __shfl_xor(rsum[r], 2);
      rsum[r] += __shfl_xor(rsum[r], 4);
      rsum[r] += __shfl_xor(rsum[r], 8);
      // d2m >= 4e6 <=> no same-batch centroid -> exact-zero row
      sc[r] = (d2m[r] < 4.0e6f) ? 1.0f / rsum[r] : 0.f;
    }

    // ---- epilogue: GEMM2 + unpack e + store (one base, imm offsets)
    const uint4* cenb = (const uint4*)cen_ws;
    float* ob = out + (size_t)(tile * 16 + q * 4) * MM + c;
#pragma unroll
    for (int mt = 0; mt < 16; mt++) {
      U16x8 b0, b1;
      b0.u = cenb[(mt * 16 + c) * 8 + q];
      b1.u = cenb[(mt * 16 + c) * 8 + 4 + q];
      f32x4 dacc = {0, 0, 0, 0};
      dacc = __builtin_amdgcn_mfma_f32_16x16x32_bf16(a0.v, b0.v, dacc, 0, 0, 0);
      dacc = __builtin_amdgcn_mfma_f32_16x16x32_bf16(a1.v, b1.v, dacc, 0, 0, 0);
      UH2 p0, p1; p0.u = ep[mt].x; p1.u = ep[mt].y;
      ob[0 * MM + mt * 16] = dacc[0] * ((float)p0.h[0] * sc[0]);
      ob[1 * MM + mt * 16] = dacc[1] * ((float)p0.h[1] * sc[1]);
      ob[2 * MM + mt * 16] = dacc[2] * ((float)p1.h[0] * sc[2]);
      ob[3 * MM + mt * 16] = dacc[3] * ((float)p1.h[1] * sc[3]);
    }
  }
}

extern "C" void kernel_launch(void* const* d_in, const int* in_sizes, int n_in,
                              void* d_out, int out_size, void* d_ws, size_t ws_size,
                              hipStream_t stream) {
  const int* clu_coords = (const int*)d_in[0];
  const int* cen_coords = (const int*)d_in[1];
  const float* clu_feats = (const float*)d_in[2];
  const float* cen_feats = (const float*)d_in[3];
  const float* conf      = (const float*)d_in[4];
  const float* W         = (const float*)d_in[5];
  const float* bvec      = (const float*)d_in[6];
  float* out = (float*)d_out;

  char* ws = (char*)d_ws;
  unsigned short* cen_ws = (unsigned short*)ws;              // 32768 B
  unsigned short* wt_ws  = (unsigned short*)(ws + 32768);    // 16384 B
  float4* cmeta_ws       = (float4*)(ws + 32768 + 16384);    // 4096 B

  prep_kernel<<<17, 256, 0, stream>>>(cen_coords, cen_feats, conf, W, bvec,
                                      cen_ws, wt_ws, cmeta_ws);
  main_kernel<<<(NJOBS + 3) / 4, 256, 0, stream>>>(
      (const int4*)clu_coords, clu_feats, bvec, cen_ws, wt_ws, cmeta_ws, out);
}

// Round 7
// 200.652 us; speedup vs baseline: 1.0496x; 1.0098x over previous
//
#include <hip/hip_runtime.h>
#include <stdint.h>

// InstanceHead on MI355X — f32/int32 inputs, f32 OUTPUT buffer.
// N=100000, M=256, B=8, L=128, D=64.
// R12: TRANSPOSED GEMM2 — swap MFMA operands: mfma(cen, clu) so the D
// fragment is out[cen][clu]^T: lane (c,q) owns output ROW c with 4
// CONSECUTIVE cols (mt*16+q*4+r).  Consequences:
//   - stores: 64 scattered dwords -> 16 dwordx4 (4x fewer VMEM insts in the
//     vmcnt-serialized epilogue)
//   - dmin/rsum are per-lane SCALARS, reduced over the row's 4 lanes with
//     shfl_xor 16,32 (2-deep chains; was 4-deep x 4 rows; 48 -> 20 shuffles)
//   - 1 coord load / 3 coord regs per lane (was 4 loads / 12 regs)
// Evidence base: R7-R11 show waves ~90% stalled in serialized waitcnts
// (lifetime ~30us vs ~3us issue); every VGPR increase lost.  This round cuts
// exposed-latency events AND register state.  __launch_bounds__(256,5)
// targets 5 waves/SIMD.  ep packed f16x2 (32 regs); batch validity geometric
// (x += 4096*batch, exact in-batch, cross-batch exp -> exact 0, empty-row
// gate d2m < 4e6); cmeta LDS-staged (imm-offset ds_reads, one base reg).

#define NN 100000
#define MM 256
#define LL 128
#define DD 64
#define NTILES (NN / 16)  // 6250, exact

typedef float f32x4 __attribute__((ext_vector_type(4)));
typedef __bf16 bf16x8 __attribute__((ext_vector_type(8)));
typedef __fp16 fp16x2 __attribute__((ext_vector_type(2)));

union U16x8 { uint4 u; bf16x8 v; unsigned short s[8]; };
union UH2 { unsigned int u; fp16x2 h; };

static __device__ __forceinline__ unsigned short f2bf(float f) {
  union { float f; unsigned int i; } t; t.f = f;
  unsigned int x = t.i;
  x += 0x7fffu + ((x >> 16) & 1u);  // round-to-nearest-even
  return (unsigned short)(x >> 16);
}

// ---------------- prep: cen (bf16), W^T (bf16), centroid meta ----------------
__global__ __launch_bounds__(256) void prep_kernel(
    const int* __restrict__ cen_coords,
    const float* __restrict__ cen_feats,
    const float* __restrict__ conf,
    const float* __restrict__ W,
    const float* __restrict__ bvec,
    unsigned short* __restrict__ cen_ws,   // [256][64] bf16
    unsigned short* __restrict__ wt_ws,    // [64][128] bf16 (W transposed)
    float4* __restrict__ cmeta_ws)         // [256] {x+4096*batch, y, z, 0}
{
  int tid = threadIdx.x;
  if (blockIdx.x < 16) {
    int m = blockIdx.x * 16 + (tid >> 4);
    int c = tid & 15;
    float a0 = 0.f, a1 = 0.f, a2 = 0.f, a3 = 0.f;
    for (int l = 0; l < LL; l++) {
      float f = cen_feats[m * LL + l];
      const float* wr = W + l * DD + c;
      a0 += f * wr[0];  a1 += f * wr[16];
      a2 += f * wr[32]; a3 += f * wr[48];
    }
    float cf = conf[m];
    cen_ws[m * DD + c +  0] = f2bf(cf * (a0 + bvec[c +  0]));
    cen_ws[m * DD + c + 16] = f2bf(cf * (a1 + bvec[c + 16]));
    cen_ws[m * DD + c + 32] = f2bf(cf * (a2 + bvec[c + 32]));
    cen_ws[m * DD + c + 48] = f2bf(cf * (a3 + bvec[c + 48]));
  } else {
    for (int i = tid; i < LL * DD; i += 256) {
      int l = i >> 6, d = i & 63;
      wt_ws[d * LL + l] = f2bf(W[l * DD + d]);
    }
    {
      int4 cc = ((const int4*)cen_coords)[tid];  // {batch, x, y, z}
      float4 f;
      f.x = (float)cc.y + 4096.0f * (float)cc.x;  // batch folded into x
      f.y = (float)cc.z;
      f.z = (float)cc.w;
      f.w = 0.0f;
      cmeta_ws[tid] = f;
    }
  }
}

// ---------------- main: fused, 1 wave per tile, transposed epilogue ----------------
__global__ __launch_bounds__(256, 5) void main_kernel(
    const int4* __restrict__ clu_coords4,
    const float* __restrict__ feats,
    const float* __restrict__ bvec,
    const unsigned short* __restrict__ cen_ws,
    const unsigned short* __restrict__ wt_ws,
    const float4* __restrict__ cmeta,
    float* __restrict__ out)
{
  __shared__ __align__(16) unsigned short clu_s[4][16 * 72];  // wave-private
  __shared__ __align__(16) float4 cmeta_s[MM];                // block-shared

  int tid = threadIdx.x;
  cmeta_s[tid] = cmeta[tid];   // stage once per block
  __syncthreads();             // before any divergent exit

  int wave = tid >> 6, lane = tid & 63;
  int q = lane >> 4, c = lane & 15;
  int tile = blockIdx.x * 4 + wave;
  if (tile >= NTILES) return;

  // ---- long-latency loads first: feats (8x dwordx4) + this lane's ROW coord
  const float4* fb = (const float4*)(feats + (size_t)(tile * 16 + c) * LL);
  float4 ff[8];
#pragma unroll
  for (int ks = 0; ks < 4; ks++) {
    ff[2 * ks]     = fb[ks * 8 + q * 2];
    ff[2 * ks + 1] = fb[ks * 8 + q * 2 + 1];
  }
  int4 rm = clu_coords4[tile * 16 + c];  // one row per lane (4-way broadcast)
  float rx = (float)rm.y + 4096.0f * (float)rm.x;  // batch folded, exact
  float ry = (float)rm.z;
  float rz = (float)rm.w;

  // ---- GEMM1: clu = feats @ W (+b)
  f32x4 acc[4] = {{0,0,0,0},{0,0,0,0},{0,0,0,0},{0,0,0,0}};
  {
    const uint4* wb = (const uint4*)wt_ws;
#pragma unroll
    for (int ks = 0; ks < 4; ks++) {
      float4 f0 = ff[2 * ks], f1 = ff[2 * ks + 1];
      U16x8 a;
      a.v[0] = (__bf16)f0.x; a.v[1] = (__bf16)f0.y; a.v[2] = (__bf16)f0.z; a.v[3] = (__bf16)f0.w;
      a.v[4] = (__bf16)f1.x; a.v[5] = (__bf16)f1.y; a.v[6] = (__bf16)f1.z; a.v[7] = (__bf16)f1.w;
#pragma unroll
      for (int nt = 0; nt < 4; nt++) {
        U16x8 b; b.u = wb[(nt * 16 + c) * 16 + ks * 4 + q];
        acc[nt] = __builtin_amdgcn_mfma_f32_16x16x32_bf16(a.v, b.v, acc[nt], 0, 0, 0);
      }
    }
  }
#pragma unroll
  for (int nt = 0; nt < 4; nt++) {
    float bv = bvec[nt * 16 + c];
    acc[nt][0] += bv; acc[nt][1] += bv; acc[nt][2] += bv; acc[nt][3] += bv;
  }
  // ---- row L2 norms (GEMM1 fragment rows q*4+r live across quad q's lanes)
  float inv_nrm[4];
#pragma unroll
  for (int r = 0; r < 4; r++) {
    float s = acc[0][r]*acc[0][r] + acc[1][r]*acc[1][r] + acc[2][r]*acc[2][r] + acc[3][r]*acc[3][r];
    s += __shfl_xor(s, 1); s += __shfl_xor(s, 2); s += __shfl_xor(s, 4); s += __shfl_xor(s, 8);
    inv_nrm[r] = 1.0f / fmaxf(sqrtf(s), 1e-12f);
  }
  // normalized clu -> LDS (bf16); inv_nrm applied HERE only
#pragma unroll
  for (int nt = 0; nt < 4; nt++)
#pragma unroll
    for (int r = 0; r < 4; r++) {
      union { __bf16 h; unsigned short s; } u;
      u.h = (__bf16)(acc[nt][r] * inv_nrm[r]);
      clu_s[wave][(q * 4 + r) * 72 + nt * 16 + c] = u.s;
    }

  // wave-private LDS transpose: DS pipe is in-order per wave, no barrier
  __builtin_amdgcn_sched_barrier(0);

  // ---- clu frags (B-operand of the swapped GEMM2): row c, k-slice q
  const uint4* cb = (const uint4*)(clu_s[wave]);
  U16x8 a0, a1;
  a0.u = cb[c * 9 + q];       // k = q*8 .. q*8+7
  a1.u = cb[c * 9 + 4 + q];   // k = 32+q*8 ..

  // ---- pass 1: d^2 min for (row c, cols mt*16+q*4+r) — per-lane scalar
  float d2m = 1e30f;
#pragma unroll
  for (int mt = 0; mt < 16; mt++) {
#pragma unroll
    for (int r = 0; r < 4; r++) {
      float4 cm = cmeta_s[mt * 16 + q * 4 + r];
      float dx = rx - cm.x, dy = ry - cm.y, dz = rz - cm.z;
      d2m = fminf(d2m, dx * dx + dy * dy + dz * dz);
    }
  }
  // reduce over the row's 4 lanes (same c, q=0..3 -> xor bits 4,5)
  d2m = fminf(d2m, __shfl_xor(d2m, 16));
  d2m = fminf(d2m, __shfl_xor(d2m, 32));
  float dmv = fmaxf(sqrtf(d2m), 0.1f);  // softmax reference (row min dist)

  // ---- pass 2: e = exp(dmin - d) once; pack f16x2 along r; row sum
  uint2 ep[16];
  float rsum = 0.f;
#pragma unroll
  for (int mt = 0; mt < 16; mt++) {
    float e[4];
#pragma unroll
    for (int r = 0; r < 4; r++) {
      float4 cm = cmeta_s[mt * 16 + q * 4 + r];
      float dx = rx - cm.x, dy = ry - cm.y, dz = rz - cm.z;
      float d = fmaxf(sqrtf(dx * dx + dy * dy + dz * dz), 0.1f);
      e[r] = __expf(dmv - d);  // <= 1; cross-batch -> exact 0
      rsum += e[r];
    }
    UH2 p0, p1;
    p0.h = __builtin_amdgcn_cvt_pkrtz(e[0], e[1]);
    p1.h = __builtin_amdgcn_cvt_pkrtz(e[2], e[3]);
    ep[mt].x = p0.u;
    ep[mt].y = p1.u;
  }
  rsum += __shfl_xor(rsum, 16);
  rsum += __shfl_xor(rsum, 32);
  // d2m >= 4e6 <=> no same-batch centroid -> exact-zero row
  float sc = (d2m < 4.0e6f) ? 1.0f / rsum : 0.f;

  // ---- epilogue: swapped GEMM2 + unpack e + dwordx4 stores
  //      lane (c,q) reg r = out[row tile*16+c][col mt*16+q*4+r]
  const uint4* cenb = (const uint4*)cen_ws;
  float4* ob4 = (float4*)(out + (size_t)(tile * 16 + c) * MM) + q;
#pragma unroll
  for (int mt = 0; mt < 16; mt++) {
    U16x8 b0, b1;
    b0.u = cenb[(mt * 16 + c) * 8 + q];       // cen rows mt*16+c, k q*8..
    b1.u = cenb[(mt * 16 + c) * 8 + 4 + q];
    f32x4 dacc = {0, 0, 0, 0};
    dacc = __builtin_amdgcn_mfma_f32_16x16x32_bf16(b0.v, a0.v, dacc, 0, 0, 0);  // SWAPPED
    dacc = __builtin_amdgcn_mfma_f32_16x16x32_bf16(b1.v, a1.v, dacc, 0, 0, 0);
    UH2 p0, p1; p0.u = ep[mt].x; p1.u = ep[mt].y;
    float4 v;
    v.x = dacc[0] * ((float)p0.h[0] * sc);
    v.y = dacc[1] * ((float)p0.h[1] * sc);
    v.z = dacc[2] * ((float)p1.h[0] * sc);
    v.w = dacc[3] * ((float)p1.h[1] * sc);
    ob4[mt * 4] = v;   // imm offset mt*64B, one base per lane
  }
}

extern "C" void kernel_launch(void* const* d_in, const int* in_sizes, int n_in,
                              void* d_out, int out_size, void* d_ws, size_t ws_size,
                              hipStream_t stream) {
  const int* clu_coords = (const int*)d_in[0];
  const int* cen_coords = (const int*)d_in[1];
  const float* clu_feats = (const float*)d_in[2];
  const float* cen_feats = (const float*)d_in[3];
  const float* conf      = (const float*)d_in[4];
  const float* W         = (const float*)d_in[5];
  const float* bvec      = (const float*)d_in[6];
  float* out = (float*)d_out;

  char* ws = (char*)d_ws;
  unsigned short* cen_ws = (unsigned short*)ws;              // 32768 B
  unsigned short* wt_ws  = (unsigned short*)(ws + 32768);    // 16384 B
  float4* cmeta_ws       = (float4*)(ws + 32768 + 16384);    // 4096 B

  prep_kernel<<<17, 256, 0, stream>>>(cen_coords, cen_feats, conf, W, bvec,
                                      cen_ws, wt_ws, cmeta_ws);
  main_kernel<<<(NTILES + 3) / 4, 256, 0, stream>>>(
      (const int4*)clu_coords, clu_feats, bvec, cen_ws, wt_ws, cmeta_ws, out);
}

// Round 8
// 198.263 us; speedup vs baseline: 1.0623x; 1.0121x over previous
//
#include <hip/hip_runtime.h>
#include <stdint.h>

// InstanceHead on MI355X — f32/int32 inputs, f32 OUTPUT buffer.
// N=100000, M=256, B=8, L=128, D=64.
// R13: R12's per-wave code unchanged (48 VGPR, transposed GEMM2, scalar
// reductions, dwordx4 stores) — repackaged into 1024-thread blocks.
// Evidence: R12 closed the model — 2.7 resident waves/SIMD x 11.7% VALU
// duty = the measured 30% VALUBusy; VGPR/LDS/wave-cap all permit ~8x more.
// Occupancy is BLOCK-DISPATCH limited (~2-3 blocks in flight per CU), not
// resource limited.  Fix: carry 16 waves per in-flight block -> 391 blocks
// x 16 tiles; whole grid (6256 waves, 24.4/CU) co-resident in one dispatch
// round.  LDS 41KB/block (clu_s 36.8K + cmeta 4K) -> 3 blocks/CU possible.
// Per-wave: ep packed f16x2; batch fold x+=4096*b (exact in-batch; cross-
// batch exp -> exact 0; empty-row gate d2m<4e6); cmeta LDS-staged.

#define NN 100000
#define MM 256
#define LL 128
#define DD 64
#define NTILES (NN / 16)  // 6250, exact
#define WPB 16            // waves (=tiles) per block

typedef float f32x4 __attribute__((ext_vector_type(4)));
typedef __bf16 bf16x8 __attribute__((ext_vector_type(8)));
typedef __fp16 fp16x2 __attribute__((ext_vector_type(2)));

union U16x8 { uint4 u; bf16x8 v; unsigned short s[8]; };
union UH2 { unsigned int u; fp16x2 h; };

static __device__ __forceinline__ unsigned short f2bf(float f) {
  union { float f; unsigned int i; } t; t.f = f;
  unsigned int x = t.i;
  x += 0x7fffu + ((x >> 16) & 1u);  // round-to-nearest-even
  return (unsigned short)(x >> 16);
}

// ---------------- prep: cen (bf16), W^T (bf16), centroid meta ----------------
__global__ __launch_bounds__(256) void prep_kernel(
    const int* __restrict__ cen_coords,
    const float* __restrict__ cen_feats,
    const float* __restrict__ conf,
    const float* __restrict__ W,
    const float* __restrict__ bvec,
    unsigned short* __restrict__ cen_ws,   // [256][64] bf16
    unsigned short* __restrict__ wt_ws,    // [64][128] bf16 (W transposed)
    float4* __restrict__ cmeta_ws)         // [256] {x+4096*batch, y, z, 0}
{
  int tid = threadIdx.x;
  if (blockIdx.x < 16) {
    int m = blockIdx.x * 16 + (tid >> 4);
    int c = tid & 15;
    float a0 = 0.f, a1 = 0.f, a2 = 0.f, a3 = 0.f;
    for (int l = 0; l < LL; l++) {
      float f = cen_feats[m * LL + l];
      const float* wr = W + l * DD + c;
      a0 += f * wr[0];  a1 += f * wr[16];
      a2 += f * wr[32]; a3 += f * wr[48];
    }
    float cf = conf[m];
    cen_ws[m * DD + c +  0] = f2bf(cf * (a0 + bvec[c +  0]));
    cen_ws[m * DD + c + 16] = f2bf(cf * (a1 + bvec[c + 16]));
    cen_ws[m * DD + c + 32] = f2bf(cf * (a2 + bvec[c + 32]));
    cen_ws[m * DD + c + 48] = f2bf(cf * (a3 + bvec[c + 48]));
  } else {
    for (int i = tid; i < LL * DD; i += 256) {
      int l = i >> 6, d = i & 63;
      wt_ws[d * LL + l] = f2bf(W[l * DD + d]);
    }
    {
      int4 cc = ((const int4*)cen_coords)[tid];  // {batch, x, y, z}
      float4 f;
      f.x = (float)cc.y + 4096.0f * (float)cc.x;  // batch folded into x
      f.y = (float)cc.z;
      f.z = (float)cc.w;
      f.w = 0.0f;
      cmeta_ws[tid] = f;
    }
  }
}

// ---------------- main: 1024-thread blocks, 16 waves = 16 tiles ----------------
__global__ __launch_bounds__(1024) void main_kernel(
    const int4* __restrict__ clu_coords4,
    const float* __restrict__ feats,
    const float* __restrict__ bvec,
    const unsigned short* __restrict__ cen_ws,
    const unsigned short* __restrict__ wt_ws,
    const float4* __restrict__ cmeta,
    float* __restrict__ out)
{
  __shared__ __align__(16) unsigned short clu_s[WPB][16 * 72];  // wave-private
  __shared__ __align__(16) float4 cmeta_s[MM];                  // block-shared

  int tid = threadIdx.x;
  if (tid < MM) cmeta_s[tid] = cmeta[tid];   // stage once per block
  __syncthreads();                           // before any divergent exit

  int wave = tid >> 6, lane = tid & 63;
  int q = lane >> 4, c = lane & 15;
  int tile = blockIdx.x * WPB + wave;
  if (tile >= NTILES) return;

  // ---- long-latency loads first: feats (8x dwordx4) + this lane's ROW coord
  const float4* fb = (const float4*)(feats + (size_t)(tile * 16 + c) * LL);
  float4 ff[8];
#pragma unroll
  for (int ks = 0; ks < 4; ks++) {
    ff[2 * ks]     = fb[ks * 8 + q * 2];
    ff[2 * ks + 1] = fb[ks * 8 + q * 2 + 1];
  }
  int4 rm = clu_coords4[tile * 16 + c];  // one row per lane (4-way broadcast)
  float rx = (float)rm.y + 4096.0f * (float)rm.x;  // batch folded, exact
  float ry = (float)rm.z;
  float rz = (float)rm.w;

  // ---- GEMM1: clu = feats @ W (+b)
  f32x4 acc[4] = {{0,0,0,0},{0,0,0,0},{0,0,0,0},{0,0,0,0}};
  {
    const uint4* wb = (const uint4*)wt_ws;
#pragma unroll
    for (int ks = 0; ks < 4; ks++) {
      float4 f0 = ff[2 * ks], f1 = ff[2 * ks + 1];
      U16x8 a;
      a.v[0] = (__bf16)f0.x; a.v[1] = (__bf16)f0.y; a.v[2] = (__bf16)f0.z; a.v[3] = (__bf16)f0.w;
      a.v[4] = (__bf16)f1.x; a.v[5] = (__bf16)f1.y; a.v[6] = (__bf16)f1.z; a.v[7] = (__bf16)f1.w;
#pragma unroll
      for (int nt = 0; nt < 4; nt++) {
        U16x8 b; b.u = wb[(nt * 16 + c) * 16 + ks * 4 + q];
        acc[nt] = __builtin_amdgcn_mfma_f32_16x16x32_bf16(a.v, b.v, acc[nt], 0, 0, 0);
      }
    }
  }
#pragma unroll
  for (int nt = 0; nt < 4; nt++) {
    float bv = bvec[nt * 16 + c];
    acc[nt][0] += bv; acc[nt][1] += bv; acc[nt][2] += bv; acc[nt][3] += bv;
  }
  // ---- row L2 norms (GEMM1 fragment rows q*4+r live across quad q's lanes)
  float inv_nrm[4];
#pragma unroll
  for (int r = 0; r < 4; r++) {
    float s = acc[0][r]*acc[0][r] + acc[1][r]*acc[1][r] + acc[2][r]*acc[2][r] + acc[3][r]*acc[3][r];
    s += __shfl_xor(s, 1); s += __shfl_xor(s, 2); s += __shfl_xor(s, 4); s += __shfl_xor(s, 8);
    inv_nrm[r] = 1.0f / fmaxf(sqrtf(s), 1e-12f);
  }
  // normalized clu -> LDS (bf16); inv_nrm applied HERE only
#pragma unroll
  for (int nt = 0; nt < 4; nt++)
#pragma unroll
    for (int r = 0; r < 4; r++) {
      union { __bf16 h; unsigned short s; } u;
      u.h = (__bf16)(acc[nt][r] * inv_nrm[r]);
      clu_s[wave][(q * 4 + r) * 72 + nt * 16 + c] = u.s;
    }

  // wave-private LDS transpose: DS pipe is in-order per wave, no barrier
  __builtin_amdgcn_sched_barrier(0);

  // ---- clu frags (B-operand of the swapped GEMM2): row c, k-slice q
  const uint4* cb = (const uint4*)(clu_s[wave]);
  U16x8 a0, a1;
  a0.u = cb[c * 9 + q];       // k = q*8 .. q*8+7
  a1.u = cb[c * 9 + 4 + q];   // k = 32+q*8 ..

  // ---- pass 1: d^2 min for (row c, cols mt*16+q*4+r) — per-lane scalar
  float d2m = 1e30f;
#pragma unroll
  for (int mt = 0; mt < 16; mt++) {
#pragma unroll
    for (int r = 0; r < 4; r++) {
      float4 cm = cmeta_s[mt * 16 + q * 4 + r];
      float dx = rx - cm.x, dy = ry - cm.y, dz = rz - cm.z;
      d2m = fminf(d2m, dx * dx + dy * dy + dz * dz);
    }
  }
  // reduce over the row's 4 lanes (same c, q=0..3 -> xor bits 4,5)
  d2m = fminf(d2m, __shfl_xor(d2m, 16));
  d2m = fminf(d2m, __shfl_xor(d2m, 32));
  float dmv = fmaxf(sqrtf(d2m), 0.1f);  // softmax reference (row min dist)

  // ---- pass 2: e = exp(dmin - d) once; pack f16x2 along r; row sum
  uint2 ep[16];
  float rsum = 0.f;
#pragma unroll
  for (int mt = 0; mt < 16; mt++) {
    float e[4];
#pragma unroll
    for (int r = 0; r < 4; r++) {
      float4 cm = cmeta_s[mt * 16 + q * 4 + r];
      float dx = rx - cm.x, dy = ry - cm.y, dz = rz - cm.z;
      float d = fmaxf(sqrtf(dx * dx + dy * dy + dz * dz), 0.1f);
      e[r] = __expf(dmv - d);  // <= 1; cross-batch -> exact 0
      rsum += e[r];
    }
    UH2 p0, p1;
    p0.h = __builtin_amdgcn_cvt_pkrtz(e[0], e[1]);
    p1.h = __builtin_amdgcn_cvt_pkrtz(e[2], e[3]);
    ep[mt].x = p0.u;
    ep[mt].y = p1.u;
  }
  rsum += __shfl_xor(rsum, 16);
  rsum += __shfl_xor(rsum, 32);
  // d2m >= 4e6 <=> no same-batch centroid -> exact-zero row
  float sc = (d2m < 4.0e6f) ? 1.0f / rsum : 0.f;

  // ---- epilogue: swapped GEMM2 + unpack e + dwordx4 stores
  //      lane (c,q) reg r = out[row tile*16+c][col mt*16+q*4+r]
  const uint4* cenb = (const uint4*)cen_ws;
  float4* ob4 = (float4*)(out + (size_t)(tile * 16 + c) * MM) + q;
#pragma unroll
  for (int mt = 0; mt < 16; mt++) {
    U16x8 b0, b1;
    b0.u = cenb[(mt * 16 + c) * 8 + q];       // cen rows mt*16+c, k q*8..
    b1.u = cenb[(mt * 16 + c) * 8 + 4 + q];
    f32x4 dacc = {0, 0, 0, 0};
    dacc = __builtin_amdgcn_mfma_f32_16x16x32_bf16(b0.v, a0.v, dacc, 0, 0, 0);  // SWAPPED
    dacc = __builtin_amdgcn_mfma_f32_16x16x32_bf16(b1.v, a1.v, dacc, 0, 0, 0);
    UH2 p0, p1; p0.u = ep[mt].x; p1.u = ep[mt].y;
    float4 v;
    v.x = dacc[0] * ((float)p0.h[0] * sc);
    v.y = dacc[1] * ((float)p0.h[1] * sc);
    v.z = dacc[2] * ((float)p1.h[0] * sc);
    v.w = dacc[3] * ((float)p1.h[1] * sc);
    ob4[mt * 4] = v;   // imm offset mt*64B, one base per lane
  }
}

extern "C" void kernel_launch(void* const* d_in, const int* in_sizes, int n_in,
                              void* d_out, int out_size, void* d_ws, size_t ws_size,
                              hipStream_t stream) {
  const int* clu_coords = (const int*)d_in[0];
  const int* cen_coords = (const int*)d_in[1];
  const float* clu_feats = (const float*)d_in[2];
  const float* cen_feats = (const float*)d_in[3];
  const float* conf      = (const float*)d_in[4];
  const float* W         = (const float*)d_in[5];
  const float* bvec      = (const float*)d_in[6];
  float* out = (float*)d_out;

  char* ws = (char*)d_ws;
  unsigned short* cen_ws = (unsigned short*)ws;              // 32768 B
  unsigned short* wt_ws  = (unsigned short*)(ws + 32768);    // 16384 B
  float4* cmeta_ws       = (float4*)(ws + 32768 + 16384);    // 4096 B

  prep_kernel<<<17, 256, 0, stream>>>(cen_coords, cen_feats, conf, W, bvec,
                                      cen_ws, wt_ws, cmeta_ws);
  main_kernel<<<(NTILES + WPB - 1) / WPB, 1024, 0, stream>>>(
      (const int4*)clu_coords, clu_feats, bvec, cen_ws, wt_ws, cmeta_ws, out);
}

// Round 9
// 191.330 us; speedup vs baseline: 1.1008x; 1.0362x over previous
//
#include <hip/hip_runtime.h>
#include <stdint.h>

// InstanceHead on MI355X — f32/int32 inputs, f32 OUTPUT buffer.
// N=100000, M=256, B=8, L=128, D=64.
// R14: R12 structure + EXPLICIT MLP.  Evidence: R7-R13 pinned at 76-85us
// across every packaging (4/16-wave blocks, 48-100 VGPR, stores/shuffles);
// occupancy counter never moves.  Model fit says per-wave lifetime is
// ~100K+ cycles = ~200 memory ops run SERIALLY — the register-minimizing
// scheduler (VGPR 48!) issues each load right before its use.  Fix: give
// the scheduler register budget AND batch loads explicitly:
//   1. __launch_bounds__(256,3): cap ~170 VGPR.
//   2. GEMM1: preload ALL 16 W-frags (64 regs) before the MFMA chain.
//   3. epilogue: 4-deep software pipeline on cen frags (prefetch next 4 mt
//      while computing current 4) — 32 serial loads -> 4 bursts of 8.
// Keeps: transposed GEMM2 (mfma(cen,clu) -> row-c lanes, dwordx4 stores),
// scalar dmin/rsum reductions (shfl_xor 16,32), ep packed f16x2, geometric
// batch fold (x+=4096*b; cross-batch exp -> exact 0; gate d2m<4e6),
// cmeta LDS-staged, wave-private clu_s transpose (no block barrier).

#define NN 100000
#define MM 256
#define LL 128
#define DD 64
#define NTILES (NN / 16)  // 6250, exact

typedef float f32x4 __attribute__((ext_vector_type(4)));
typedef __bf16 bf16x8 __attribute__((ext_vector_type(8)));
typedef __fp16 fp16x2 __attribute__((ext_vector_type(2)));

union U16x8 { uint4 u; bf16x8 v; unsigned short s[8]; };
union UH2 { unsigned int u; fp16x2 h; };

static __device__ __forceinline__ unsigned short f2bf(float f) {
  union { float f; unsigned int i; } t; t.f = f;
  unsigned int x = t.i;
  x += 0x7fffu + ((x >> 16) & 1u);  // round-to-nearest-even
  return (unsigned short)(x >> 16);
}

// ---------------- prep: cen (bf16), W^T (bf16), centroid meta ----------------
__global__ __launch_bounds__(256) void prep_kernel(
    const int* __restrict__ cen_coords,
    const float* __restrict__ cen_feats,
    const float* __restrict__ conf,
    const float* __restrict__ W,
    const float* __restrict__ bvec,
    unsigned short* __restrict__ cen_ws,   // [256][64] bf16
    unsigned short* __restrict__ wt_ws,    // [64][128] bf16 (W transposed)
    float4* __restrict__ cmeta_ws)         // [256] {x+4096*batch, y, z, 0}
{
  int tid = threadIdx.x;
  if (blockIdx.x < 16) {
    int m = blockIdx.x * 16 + (tid >> 4);
    int c = tid & 15;
    float a0 = 0.f, a1 = 0.f, a2 = 0.f, a3 = 0.f;
    for (int l = 0; l < LL; l++) {
      float f = cen_feats[m * LL + l];
      const float* wr = W + l * DD + c;
      a0 += f * wr[0];  a1 += f * wr[16];
      a2 += f * wr[32]; a3 += f * wr[48];
    }
    float cf = conf[m];
    cen_ws[m * DD + c +  0] = f2bf(cf * (a0 + bvec[c +  0]));
    cen_ws[m * DD + c + 16] = f2bf(cf * (a1 + bvec[c + 16]));
    cen_ws[m * DD + c + 32] = f2bf(cf * (a2 + bvec[c + 32]));
    cen_ws[m * DD + c + 48] = f2bf(cf * (a3 + bvec[c + 48]));
  } else {
    for (int i = tid; i < LL * DD; i += 256) {
      int l = i >> 6, d = i & 63;
      wt_ws[d * LL + l] = f2bf(W[l * DD + d]);
    }
    {
      int4 cc = ((const int4*)cen_coords)[tid];  // {batch, x, y, z}
      float4 f;
      f.x = (float)cc.y + 4096.0f * (float)cc.x;  // batch folded into x
      f.y = (float)cc.z;
      f.z = (float)cc.w;
      f.w = 0.0f;
      cmeta_ws[tid] = f;
    }
  }
}

// ---------------- main: fused, 1 wave/tile, explicit-MLP version ----------------
__global__ __launch_bounds__(256, 3) void main_kernel(
    const int4* __restrict__ clu_coords4,
    const float* __restrict__ feats,
    const float* __restrict__ bvec,
    const unsigned short* __restrict__ cen_ws,
    const unsigned short* __restrict__ wt_ws,
    const float4* __restrict__ cmeta,
    float* __restrict__ out)
{
  __shared__ __align__(16) unsigned short clu_s[4][16 * 72];  // wave-private
  __shared__ __align__(16) float4 cmeta_s[MM];                // block-shared

  int tid = threadIdx.x;
  cmeta_s[tid] = cmeta[tid];   // stage once per block
  __syncthreads();             // before any divergent exit

  int wave = tid >> 6, lane = tid & 63;
  int q = lane >> 4, c = lane & 15;
  int tile = blockIdx.x * 4 + wave;
  if (tile >= NTILES) return;

  // ---- batched long-latency loads: feats (8x dwordx4), W frags (16x dwordx4),
  //      row coord — ALL issued before any dependent compute.
  const float4* fb = (const float4*)(feats + (size_t)(tile * 16 + c) * LL);
  float4 ff[8];
#pragma unroll
  for (int ks = 0; ks < 4; ks++) {
    ff[2 * ks]     = fb[ks * 8 + q * 2];
    ff[2 * ks + 1] = fb[ks * 8 + q * 2 + 1];
  }
  const uint4* wb = (const uint4*)wt_ws;
  uint4 wbv[16];
#pragma unroll
  for (int ks = 0; ks < 4; ks++)
#pragma unroll
    for (int nt = 0; nt < 4; nt++)
      wbv[ks * 4 + nt] = wb[(nt * 16 + c) * 16 + ks * 4 + q];
  int4 rm = clu_coords4[tile * 16 + c];  // one row per lane (4-way broadcast)
  float rx = (float)rm.y + 4096.0f * (float)rm.x;  // batch folded, exact
  float ry = (float)rm.z;
  float rz = (float)rm.w;

  // ---- GEMM1: clu = feats @ W (+b)
  f32x4 acc[4] = {{0,0,0,0},{0,0,0,0},{0,0,0,0},{0,0,0,0}};
#pragma unroll
  for (int ks = 0; ks < 4; ks++) {
    float4 f0 = ff[2 * ks], f1 = ff[2 * ks + 1];
    U16x8 a;
    a.v[0] = (__bf16)f0.x; a.v[1] = (__bf16)f0.y; a.v[2] = (__bf16)f0.z; a.v[3] = (__bf16)f0.w;
    a.v[4] = (__bf16)f1.x; a.v[5] = (__bf16)f1.y; a.v[6] = (__bf16)f1.z; a.v[7] = (__bf16)f1.w;
#pragma unroll
    for (int nt = 0; nt < 4; nt++) {
      U16x8 b; b.u = wbv[ks * 4 + nt];
      acc[nt] = __builtin_amdgcn_mfma_f32_16x16x32_bf16(a.v, b.v, acc[nt], 0, 0, 0);
    }
  }
#pragma unroll
  for (int nt = 0; nt < 4; nt++) {
    float bv = bvec[nt * 16 + c];
    acc[nt][0] += bv; acc[nt][1] += bv; acc[nt][2] += bv; acc[nt][3] += bv;
  }
  // ---- row L2 norms (GEMM1 fragment rows q*4+r live across quad q's lanes)
  float inv_nrm[4];
#pragma unroll
  for (int r = 0; r < 4; r++) {
    float s = acc[0][r]*acc[0][r] + acc[1][r]*acc[1][r] + acc[2][r]*acc[2][r] + acc[3][r]*acc[3][r];
    s += __shfl_xor(s, 1); s += __shfl_xor(s, 2); s += __shfl_xor(s, 4); s += __shfl_xor(s, 8);
    inv_nrm[r] = 1.0f / fmaxf(sqrtf(s), 1e-12f);
  }
  // normalized clu -> LDS (bf16); inv_nrm applied HERE only
#pragma unroll
  for (int nt = 0; nt < 4; nt++)
#pragma unroll
    for (int r = 0; r < 4; r++) {
      union { __bf16 h; unsigned short s; } u;
      u.h = (__bf16)(acc[nt][r] * inv_nrm[r]);
      clu_s[wave][(q * 4 + r) * 72 + nt * 16 + c] = u.s;
    }

  // wave-private LDS transpose: DS pipe is in-order per wave, no barrier
  __builtin_amdgcn_sched_barrier(0);

  // ---- clu frags (B-operand of the swapped GEMM2): row c, k-slice q
  const uint4* cb = (const uint4*)(clu_s[wave]);
  U16x8 a0, a1;
  a0.u = cb[c * 9 + q];       // k = q*8 .. q*8+7
  a1.u = cb[c * 9 + 4 + q];   // k = 32+q*8 ..

  // ---- pass 1: d^2 min for (row c, cols mt*16+q*4+r) — per-lane scalar
  float d2m = 1e30f;
#pragma unroll
  for (int mt = 0; mt < 16; mt++) {
#pragma unroll
    for (int r = 0; r < 4; r++) {
      float4 cm = cmeta_s[mt * 16 + q * 4 + r];
      float dx = rx - cm.x, dy = ry - cm.y, dz = rz - cm.z;
      d2m = fminf(d2m, dx * dx + dy * dy + dz * dz);
    }
  }
  // reduce over the row's 4 lanes (same c, q=0..3 -> xor bits 4,5)
  d2m = fminf(d2m, __shfl_xor(d2m, 16));
  d2m = fminf(d2m, __shfl_xor(d2m, 32));
  float dmv = fmaxf(sqrtf(d2m), 0.1f);  // softmax reference (row min dist)

  // ---- pass 2: e = exp(dmin - d) once; pack f16x2 along r; row sum
  uint2 ep[16];
  float rsum = 0.f;
#pragma unroll
  for (int mt = 0; mt < 16; mt++) {
    float e[4];
#pragma unroll
    for (int r = 0; r < 4; r++) {
      float4 cm = cmeta_s[mt * 16 + q * 4 + r];
      float dx = rx - cm.x, dy = ry - cm.y, dz = rz - cm.z;
      float d = fmaxf(sqrtf(dx * dx + dy * dy + dz * dz), 0.1f);
      e[r] = __expf(dmv - d);  // <= 1; cross-batch -> exact 0
      rsum += e[r];
    }
    UH2 p0, p1;
    p0.h = __builtin_amdgcn_cvt_pkrtz(e[0], e[1]);
    p1.h = __builtin_amdgcn_cvt_pkrtz(e[2], e[3]);
    ep[mt].x = p0.u;
    ep[mt].y = p1.u;
  }
  rsum += __shfl_xor(rsum, 16);
  rsum += __shfl_xor(rsum, 32);
  // d2m >= 4e6 <=> no same-batch centroid -> exact-zero row
  float sc = (d2m < 4.0e6f) ? 1.0f / rsum : 0.f;

  // ---- epilogue: swapped GEMM2, 4-deep software-pipelined cen prefetch
  //      lane (c,q) reg r = out[row tile*16+c][col mt*16+q*4+r]
  const uint4* cenb = (const uint4*)cen_ws;
  float4* ob4 = (float4*)(out + (size_t)(tile * 16 + c) * MM) + q;

  uint4 pb0[4], pb1[4];
#pragma unroll
  for (int j = 0; j < 4; j++) {
    pb0[j] = cenb[((j) * 16 + c) * 8 + q];
    pb1[j] = cenb[((j) * 16 + c) * 8 + 4 + q];
  }
#pragma unroll
  for (int g = 0; g < 4; g++) {
    uint4 nb0[4], nb1[4];
    if (g < 3) {
#pragma unroll
      for (int j = 0; j < 4; j++) {
        nb0[j] = cenb[(((g + 1) * 4 + j) * 16 + c) * 8 + q];
        nb1[j] = cenb[(((g + 1) * 4 + j) * 16 + c) * 8 + 4 + q];
      }
    }
#pragma unroll
    for (int j = 0; j < 4; j++) {
      int mt = g * 4 + j;
      U16x8 b0, b1; b0.u = pb0[j]; b1.u = pb1[j];
      f32x4 dacc = {0, 0, 0, 0};
      dacc = __builtin_amdgcn_mfma_f32_16x16x32_bf16(b0.v, a0.v, dacc, 0, 0, 0);  // SWAPPED
      dacc = __builtin_amdgcn_mfma_f32_16x16x32_bf16(b1.v, a1.v, dacc, 0, 0, 0);
      UH2 p0, p1; p0.u = ep[mt].x; p1.u = ep[mt].y;
      float4 v;
      v.x = dacc[0] * ((float)p0.h[0] * sc);
      v.y = dacc[1] * ((float)p0.h[1] * sc);
      v.z = dacc[2] * ((float)p1.h[0] * sc);
      v.w = dacc[3] * ((float)p1.h[1] * sc);
      ob4[mt * 4] = v;   // imm offset mt*64B, one base per lane
    }
    if (g < 3) {
#pragma unroll
      for (int j = 0; j < 4; j++) { pb0[j] = nb0[j]; pb1[j] = nb1[j]; }
    }
  }
}

extern "C" void kernel_launch(void* const* d_in, const int* in_sizes, int n_in,
                              void* d_out, int out_size, void* d_ws, size_t ws_size,
                              hipStream_t stream) {
  const int* clu_coords = (const int*)d_in[0];
  const int* cen_coords = (const int*)d_in[1];
  const float* clu_feats = (const float*)d_in[2];
  const float* cen_feats = (const float*)d_in[3];
  const float* conf      = (const float*)d_in[4];
  const float* W         = (const float*)d_in[5];
  const float* bvec      = (const float*)d_in[6];
  float* out = (float*)d_out;

  char* ws = (char*)d_ws;
  unsigned short* cen_ws = (unsigned short*)ws;              // 32768 B
  unsigned short* wt_ws  = (unsigned short*)(ws + 32768);    // 16384 B
  float4* cmeta_ws       = (float4*)(ws + 32768 + 16384);    // 4096 B

  prep_kernel<<<17, 256, 0, stream>>>(cen_coords, cen_feats, conf, W, bvec,
                                      cen_ws, wt_ws, cmeta_ws);
  main_kernel<<<(NTILES + 3) / 4, 256, 0, stream>>>(
      (const int4*)clu_coords, clu_feats, bvec, cen_ws, wt_ws, cmeta_ws, out);
}